// Round 1
// baseline (63657.281 us; speedup 1.0000x reference)
//
#include <hip/hip_runtime.h>
#include <stdint.h>

// VanillaRNN: B=128, T=512, I=128, H=2048, O=10
// h_{t+1} = tanh(x_t @ W_hx + h_t @ W_hh + b_h); out = softmax(h_T @ W_ph + b_o)
//
// Strategy: persistent cooperative kernel, 256 WGs (1/CU), each owns a
// [32x32] tile of h. fp32 emulated via bf16 hi/lo split (3 MFMAs/k-tile).
// Grid barrier per step via cumulative atomic counter (agent scope).

#define B_   128
#define T_   512
#define I_   128
#define H_   2048
#define O_   10
#define KK   2176   // H_ + I_ (fused [h | x_t] @ [W_hh ; W_hx])
#define NWG  256
#define NTHR 512

typedef __attribute__((ext_vector_type(8))) short bf16x8;
typedef __attribute__((ext_vector_type(4))) float f32x4;
typedef __attribute__((ext_vector_type(4))) int   i32x4;

__device__ __forceinline__ unsigned short bf16_rne(float f) {
    uint32_t u = __builtin_bit_cast(uint32_t, f);
    return (unsigned short)((u + 0x7FFFu + ((u >> 16) & 1u)) >> 16);
}
__device__ __forceinline__ float bf16_to_f(unsigned short h) {
    return __builtin_bit_cast(float, (uint32_t)h << 16);
}

struct Stage { i32x4 a0, a1, b0, b1; };

__global__ void prep_init(unsigned int* cnt) {
    if (threadIdx.x == 0) *cnt = 0u;
}

// Transpose + hi/lo split: Wt[n][k] = W[k][n], k<2048 -> W_hh, k>=2048 -> W_hx.
__global__ void prep_weights(const float* __restrict__ Whh, const float* __restrict__ Whx,
                             unsigned short* __restrict__ Wt_hi, unsigned short* __restrict__ Wt_lo) {
    __shared__ float tile[32][33];
    const int kt = blockIdx.x;          // 0..67
    const int nt = blockIdx.y;          // 0..63
    const int tx = threadIdx.x & 31;
    const int ty = threadIdx.x >> 5;    // 0..7
#pragma unroll
    for (int r = ty; r < 32; r += 8) {
        const int k = kt * 32 + r;
        const int n = nt * 32 + tx;
        tile[r][tx] = (k < H_) ? Whh[(size_t)k * H_ + n] : Whx[(size_t)(k - H_) * H_ + n];
    }
    __syncthreads();
#pragma unroll
    for (int r = ty; r < 32; r += 8) {
        const int n = nt * 32 + r;
        const int k = kt * 32 + tx;
        const float v = tile[tx][r];
        const unsigned short hi = bf16_rne(v);
        const unsigned short lo = bf16_rne(v - bf16_to_f(hi));
        Wt_hi[(size_t)n * KK + k] = hi;
        Wt_lo[(size_t)n * KK + k] = lo;
    }
}

__global__ __launch_bounds__(NTHR, 2) void rnn_scan(
    const float* __restrict__ x,              // [B][T][I]
    const unsigned short* __restrict__ Wt_hi, // [H][KK]
    const unsigned short* __restrict__ Wt_lo,
    const float* __restrict__ b_h,            // [H]
    const float* __restrict__ W_ph,           // [H][O]
    const float* __restrict__ b_o,            // [O]
    unsigned short* __restrict__ h_hi0, unsigned short* __restrict__ h_lo0,
    unsigned short* __restrict__ h_hi1, unsigned short* __restrict__ h_lo1,
    float* __restrict__ out,                  // [B][O]
    unsigned int* __restrict__ cnt)
{
    const int tid  = threadIdx.x;
    const int wg   = blockIdx.x;
    const int wave = tid >> 6;
    const int lane = tid & 63;
    const int l15  = lane & 15;
    const int l4   = lane >> 4;
    const int kp   = wave & 1;        // k-parity split within quadrant
    const int q    = wave >> 1;       // quadrant 0..3
    const int mw   = q >> 1;
    const int nw   = q & 1;
    const int mb   = wg >> 6;         // row block 0..3
    const int nb   = wg & 63;         // col block 0..63 (mb-replicas share XCD)

    const int arow = mb * 32 + mw * 16 + l15;   // A row  (0..127)
    const int bcol = nb * 32 + nw * 16 + l15;   // B col  (0..2047)

    __shared__ float red[4][256];
    __shared__ float lgt[16];

    const float bb = b_h[bcol];

    for (int t = 0; t < T_; ++t) {
        const unsigned short* rhi = (t & 1) ? h_hi0 : h_hi1;  // read buf (t-1)&1
        const unsigned short* rlo = (t & 1) ? h_lo0 : h_lo1;
        unsigned short* whi = (t & 1) ? h_hi1 : h_hi0;        // write buf t&1
        unsigned short* wlo = (t & 1) ? h_lo1 : h_lo0;

        auto LOADT = [&](Stage& s, int i) {
            const int kt = kp + 2 * i;           // this wave's k-tile
            const int k0 = kt * 32 + l4 * 8;
            const size_t boff = (size_t)bcol * KK + k0;
            s.b0 = *(const i32x4*)(Wt_hi + boff);
            s.b1 = *(const i32x4*)(Wt_lo + boff);
            if (i < 32) {                        // h part
                const size_t aoff = (size_t)arow * H_ + k0;
                s.a0 = *(const i32x4*)(rhi + aoff);
                s.a1 = *(const i32x4*)(rlo + aoff);
            } else {                             // x part (fp32, split at consume)
                const size_t xoff = ((size_t)arow * T_ + t) * (size_t)I_ + (size_t)(k0 - H_);
                s.a0 = *(const i32x4*)(x + xoff);
                s.a1 = *(const i32x4*)(x + xoff + 4);
            }
        };

        f32x4 c0 = {0.f,0.f,0.f,0.f}, c1 = {0.f,0.f,0.f,0.f}, c2 = {0.f,0.f,0.f,0.f};

        auto CONSUME = [&](const Stage& s, int i) {
            bf16x8 ah, al;
            const bf16x8 bh = __builtin_bit_cast(bf16x8, s.b0);
            const bf16x8 bl = __builtin_bit_cast(bf16x8, s.b1);
            if (i < 32) {
                ah = __builtin_bit_cast(bf16x8, s.a0);
                al = __builtin_bit_cast(bf16x8, s.a1);
            } else {
                const f32x4 f0 = __builtin_bit_cast(f32x4, s.a0);
                const f32x4 f1 = __builtin_bit_cast(f32x4, s.a1);
#pragma unroll
                for (int j = 0; j < 8; ++j) {
                    const float f = (j < 4) ? f0[j] : f1[j - 4];
                    const unsigned short hi = bf16_rne(f);
                    const unsigned short lo = bf16_rne(f - bf16_to_f(hi));
                    ah[j] = (short)hi;
                    al[j] = (short)lo;
                }
            }
            // fp32-emulating product: hi*hi + hi*lo + lo*hi (3 indep acc chains)
            c0 = __builtin_amdgcn_mfma_f32_16x16x32_bf16(ah, bh, c0, 0, 0, 0);
            c1 = __builtin_amdgcn_mfma_f32_16x16x32_bf16(ah, bl, c1, 0, 0, 0);
            c2 = __builtin_amdgcn_mfma_f32_16x16x32_bf16(al, bh, c2, 0, 0, 0);
        };

        const int i0 = (t == 0) ? 32 : 0;        // t=0: h==0, only x tiles
        Stage sA, sB;
        LOADT(sA, i0);
        LOADT(sB, i0 + 1);
        int i = i0;
        for (; i + 2 < 34; i += 2) {             // depth-2 software pipeline
            CONSUME(sA, i);
            LOADT(sA, i + 2);
            CONSUME(sB, i + 1);
            if (i + 3 < 34) LOADT(sB, i + 3);
        }
        CONSUME(sA, i);
        if (i + 1 < 34) CONSUME(sB, i + 1);

        f32x4 s = c0 + c1 + c2;

        // cross-k-parity reduce via LDS
        if (kp == 1) {
            *(f32x4*)&red[q][lane << 2] = s;
        }
        __syncthreads();
        if (kp == 0) {
            s += *(const f32x4*)&red[q][lane << 2];
#pragma unroll
            for (int r = 0; r < 4; ++r) {
                const float pre = s[r] + bb;
                const float hv  = tanhf(pre);
                const unsigned short hi = bf16_rne(hv);
                const unsigned short lo = bf16_rne(hv - bf16_to_f(hi));
                const size_t off = (size_t)(mb * 32 + mw * 16 + l4 * 4 + r) * H_ + bcol;
                whi[off] = hi;
                wlo[off] = lo;
            }
        }

        // ---- grid barrier (cumulative counter, agent scope) ----
        __threadfence();                          // make h stores agent-visible
        __syncthreads();
        if (tid == 0) {
            __hip_atomic_fetch_add(cnt, 1u, __ATOMIC_RELEASE, __HIP_MEMORY_SCOPE_AGENT);
            const unsigned int target = (unsigned int)NWG * (unsigned int)(t + 1);
            while (__hip_atomic_load(cnt, __ATOMIC_RELAXED, __HIP_MEMORY_SCOPE_AGENT) < target)
                __builtin_amdgcn_s_sleep(1);
        }
        __syncthreads();
        __threadfence();                          // invalidate caches before reading new h
    }

    // ---- epilogue: logits + softmax, one WG per batch row (h_T in buf1) ----
    if (wg < B_) {
        const int b = wg;
        float o[O_];
#pragma unroll
        for (int j = 0; j < O_; ++j) o[j] = 0.f;
        for (int k = tid; k < H_; k += NTHR) {
            const float hv = bf16_to_f(h_hi1[(size_t)b * H_ + k]) + bf16_to_f(h_lo1[(size_t)b * H_ + k]);
            const float* wrow = W_ph + (size_t)k * O_;
#pragma unroll
            for (int j = 0; j < O_; ++j) o[j] += hv * wrow[j];
        }
#pragma unroll
        for (int off = 32; off > 0; off >>= 1) {
#pragma unroll
            for (int j = 0; j < O_; ++j) o[j] += __shfl_down(o[j], off);
        }
        float* rf = &red[0][0];
        if (lane == 0) {
#pragma unroll
            for (int j = 0; j < O_; ++j) rf[wave * 16 + j] = o[j];
        }
        __syncthreads();
        if (tid < O_) {
            float l = b_o[tid];
#pragma unroll
            for (int w = 0; w < 8; ++w) l += rf[w * 16 + tid];
            lgt[tid] = l;
        }
        __syncthreads();
        if (tid < O_) {
            float m = lgt[0];
#pragma unroll
            for (int j = 1; j < O_; ++j) m = fmaxf(m, lgt[j]);
            float ssum = 0.f;
#pragma unroll
            for (int j = 0; j < O_; ++j) ssum += expf(lgt[j] - m);
            out[(size_t)b * O_ + tid] = expf(lgt[tid] - m) / ssum;
        }
    }
}

extern "C" void kernel_launch(void* const* d_in, const int* in_sizes, int n_in,
                              void* d_out, int out_size, void* d_ws, size_t ws_size,
                              hipStream_t stream) {
    const float* x    = (const float*)d_in[0];
    const float* Whx  = (const float*)d_in[1];
    const float* Whh  = (const float*)d_in[2];
    const float* bh   = (const float*)d_in[3];
    const float* Wph  = (const float*)d_in[4];
    const float* bo   = (const float*)d_in[5];
    float* out = (float*)d_out;

    // ws layout (~20 MB): counter | Wt_hi | Wt_lo | h ping-pong (hi/lo x2)
    char* ws = (char*)d_ws;
    unsigned int*   cnt   = (unsigned int*)ws;
    unsigned short* Wt_hi = (unsigned short*)(ws + 256);
    unsigned short* Wt_lo = Wt_hi + (size_t)H_ * KK;
    unsigned short* h_hi0 = Wt_lo + (size_t)H_ * KK;
    unsigned short* h_lo0 = h_hi0 + (size_t)B_ * H_;
    unsigned short* h_hi1 = h_lo0 + (size_t)B_ * H_;
    unsigned short* h_lo1 = h_hi1 + (size_t)B_ * H_;

    hipLaunchKernelGGL(prep_init, dim3(1), dim3(64), 0, stream, cnt);
    hipLaunchKernelGGL(prep_weights, dim3(68, 64), dim3(256), 0, stream, Whh, Whx, Wt_hi, Wt_lo);

    void* args[] = {
        (void*)&x, (void*)&Wt_hi, (void*)&Wt_lo, (void*)&bh, (void*)&Wph, (void*)&bo,
        (void*)&h_hi0, (void*)&h_lo0, (void*)&h_hi1, (void*)&h_lo1, (void*)&out, (void*)&cnt
    };
    hipLaunchCooperativeKernel((const void*)rnn_scan, dim3(NWG), dim3(NTHR), args, 0, stream);
}

// Round 2
// 12600.416 us; speedup vs baseline: 5.0520x; 5.0520x over previous
//
#include <hip/hip_runtime.h>
#include <stdint.h>

// VanillaRNN: B=128, T=512, I=128, H=2048, O=10
// h_{t+1} = tanh(x_t @ W_hx + h_t @ W_hh + b_h); out = softmax(h_T @ W_ph + b_o)
//
// R1: persistent coop kernel. 256 WGs (1/CU), WG = [32x32] h-tile.
//   - W (hi/lo bf16 split, transposed) held in REGISTERS (136 VGPR/thread),
//     waves = 2(col-half) x 4(k-quarter).
//   - Distributed grid barrier: per-WG arrive slot (64B stride) + master go flag.
//   - fp32 emulated via 3 bf16 MFMAs (hi*hi + hi*lo + lo*hi).

#define B_   128
#define T_   512
#define I_   128
#define H_   2048
#define O_   10
#define KK   2176   // H_ + I_
#define NWG  256
#define NTHR 512

typedef __attribute__((ext_vector_type(8))) short bf16x8;
typedef __attribute__((ext_vector_type(4))) float f32x4;
typedef __attribute__((ext_vector_type(4))) int   i32x4;

__device__ __forceinline__ unsigned short bf16_rne(float f) {
    uint32_t u = __builtin_bit_cast(uint32_t, f);
    return (unsigned short)((u + 0x7FFFu + ((u >> 16) & 1u)) >> 16);
}
__device__ __forceinline__ float bf16_to_f(unsigned short h) {
    return __builtin_bit_cast(float, (uint32_t)h << 16);
}

__global__ void prep_init(unsigned int* flags) {
    for (int i = threadIdx.x; i < 5120; i += blockDim.x) flags[i] = 0u;  // 20KB
}

// Transpose + hi/lo split: Wt[n][k] = W[k][n]; k<2048 -> W_hh, k>=2048 -> W_hx.
__global__ void prep_weights(const float* __restrict__ Whh, const float* __restrict__ Whx,
                             unsigned short* __restrict__ Wt_hi, unsigned short* __restrict__ Wt_lo) {
    __shared__ float tile[32][33];
    const int kt = blockIdx.x;          // 0..67
    const int nt = blockIdx.y;          // 0..63
    const int tx = threadIdx.x & 31;
    const int ty = threadIdx.x >> 5;    // 0..7
#pragma unroll
    for (int r = ty; r < 32; r += 8) {
        const int k = kt * 32 + r;
        const int n = nt * 32 + tx;
        tile[r][tx] = (k < H_) ? Whh[(size_t)k * H_ + n] : Whx[(size_t)(k - H_) * H_ + n];
    }
    __syncthreads();
#pragma unroll
    for (int r = ty; r < 32; r += 8) {
        const int n = nt * 32 + r;
        const int k = kt * 32 + tx;
        const float v = tile[tx][r];
        const unsigned short hi = bf16_rne(v);
        const unsigned short lo = bf16_rne(v - bf16_to_f(hi));
        Wt_hi[(size_t)n * KK + k] = hi;
        Wt_lo[(size_t)n * KK + k] = lo;
    }
}

#define MFMA(a, b, c) __builtin_amdgcn_mfma_f32_16x16x32_bf16((a), (b), (c), 0, 0, 0)

__global__ __launch_bounds__(NTHR, 2) void rnn_scan(
    const float* __restrict__ x,              // [B][T][I]
    const unsigned short* __restrict__ Wt_hi, // [H][KK]
    const unsigned short* __restrict__ Wt_lo,
    const float* __restrict__ b_h,
    const float* __restrict__ W_ph,           // [H][O]
    const float* __restrict__ b_o,
    unsigned short* __restrict__ h_hi0, unsigned short* __restrict__ h_lo0,
    unsigned short* __restrict__ h_hi1, unsigned short* __restrict__ h_lo1,
    float* __restrict__ out,                  // [B][O]
    unsigned int* __restrict__ flags)
{
    const int tid  = threadIdx.x;
    const int wg   = blockIdx.x;
    const int wave = tid >> 6;
    const int lane = tid & 63;
    const int l15  = lane & 15;
    const int l4   = lane >> 4;
    const int kp   = wave & 3;        // k-quarter 0..3
    const int nw   = wave >> 2;       // col-half 0..1
    const int mb   = wg >> 6;         // row block 0..3
    const int nb   = wg & 63;         // col block 0..63 (mb-replicas share XCD)

    const int arow0 = mb * 32 + l15;          // A rows (this WG: 32 rows)
    const int arow1 = arow0 + 16;
    const int bcol  = nb * 32 + nw * 16 + l15;

    unsigned int* gof    = flags;                   // own 64B line
    unsigned int* arrive = flags + 16 + wg * 16;    // 64B stride slots

    __shared__ f32x4 red[2][3][2][64];   // [nw][kp-1][mw][lane]
    __shared__ float epi[128];
    __shared__ float lgt[16];

    const float bb = b_h[bcol];

    // ---- preload W panel into registers (constant over t) ----
    i32x4 wh[17], wl[17];
    {
        const size_t wbase = (size_t)bcol * KK + (size_t)(kp * 32 + l4 * 8);
#pragma unroll
        for (int i = 0; i < 17; ++i) {
            wh[i] = *(const i32x4*)(Wt_hi + wbase + (size_t)i * 128);
            wl[i] = *(const i32x4*)(Wt_lo + wbase + (size_t)i * 128);
        }
    }

    for (int t = 0; t < T_; ++t) {
        const unsigned short* rhi = (t & 1) ? h_hi0 : h_hi1;
        const unsigned short* rlo = (t & 1) ? h_lo0 : h_lo1;
        unsigned short* whi = (t & 1) ? h_hi1 : h_hi0;
        unsigned short* wlo = (t & 1) ? h_lo1 : h_lo0;

        f32x4 c00 = {0.f,0.f,0.f,0.f}, c01 = c00, c02 = c00;
        f32x4 c10 = c00, c11 = c00, c12 = c00;

        // ---- x tile (k-tile 64+kp): fp32 -> hi/lo split at consume ----
        {
            const int xc = kp * 32 + l4 * 8;
            const size_t x0 = ((size_t)arow0 * T_ + t) * I_ + xc;
            const size_t x1 = ((size_t)arow1 * T_ + t) * I_ + xc;
            const f32x4 xa0 = *(const f32x4*)(x + x0);
            const f32x4 xa1 = *(const f32x4*)(x + x0 + 4);
            const f32x4 xb0 = *(const f32x4*)(x + x1);
            const f32x4 xb1 = *(const f32x4*)(x + x1 + 4);
            bf16x8 ah0, al0, ah1, al1;
#pragma unroll
            for (int j = 0; j < 8; ++j) {
                const float f0 = (j < 4) ? xa0[j] : xa1[j - 4];
                const float f1 = (j < 4) ? xb0[j] : xb1[j - 4];
                const unsigned short u0 = bf16_rne(f0);
                const unsigned short u1 = bf16_rne(f1);
                ah0[j] = (short)u0; al0[j] = (short)bf16_rne(f0 - bf16_to_f(u0));
                ah1[j] = (short)u1; al1[j] = (short)bf16_rne(f1 - bf16_to_f(u1));
            }
            const bf16x8 bh = __builtin_bit_cast(bf16x8, wh[16]);
            const bf16x8 bl = __builtin_bit_cast(bf16x8, wl[16]);
            c00 = MFMA(ah0, bh, c00); c01 = MFMA(ah0, bl, c01); c02 = MFMA(al0, bh, c02);
            c10 = MFMA(ah1, bh, c10); c11 = MFMA(ah1, bl, c11); c12 = MFMA(al1, bh, c12);
        }

        // ---- h tiles: this wave's k-quarter, W from registers ----
        if (t > 0) {
            const size_t kbase = (size_t)(kp * 32 + l4 * 8);
#pragma unroll
            for (int i = 0; i < 16; ++i) {
                const size_t k0 = kbase + (size_t)i * 128;
                const size_t o0 = (size_t)arow0 * H_ + k0;
                const size_t o1 = (size_t)arow1 * H_ + k0;
                const bf16x8 ah0 = *(const bf16x8*)(rhi + o0);
                const bf16x8 al0 = *(const bf16x8*)(rlo + o0);
                const bf16x8 ah1 = *(const bf16x8*)(rhi + o1);
                const bf16x8 al1 = *(const bf16x8*)(rlo + o1);
                const bf16x8 bh = __builtin_bit_cast(bf16x8, wh[i]);
                const bf16x8 bl = __builtin_bit_cast(bf16x8, wl[i]);
                c00 = MFMA(ah0, bh, c00); c01 = MFMA(ah0, bl, c01); c02 = MFMA(al0, bh, c02);
                c10 = MFMA(ah1, bh, c10); c11 = MFMA(ah1, bl, c11); c12 = MFMA(al1, bh, c12);
            }
        }

        f32x4 s0 = c00 + c01 + c02;
        f32x4 s1 = c10 + c11 + c12;

        // ---- cross-k-quarter reduce (4 waves per nw) ----
        if (kp != 0) {
            red[nw][kp - 1][0][lane] = s0;
            red[nw][kp - 1][1][lane] = s1;
        }
        __syncthreads();
        if (kp == 0) {
#pragma unroll
            for (int p = 0; p < 3; ++p) { s0 += red[nw][p][0][lane]; s1 += red[nw][p][1][lane]; }
#pragma unroll
            for (int r = 0; r < 4; ++r) {
                {
                    const float hv = tanhf(s0[r] + bb);
                    const unsigned short hi = bf16_rne(hv);
                    const unsigned short lo = bf16_rne(hv - bf16_to_f(hi));
                    const size_t off = (size_t)(mb * 32 + l4 * 4 + r) * H_ + bcol;
                    whi[off] = hi; wlo[off] = lo;
                }
                {
                    const float hv = tanhf(s1[r] + bb);
                    const unsigned short hi = bf16_rne(hv);
                    const unsigned short lo = bf16_rne(hv - bf16_to_f(hi));
                    const size_t off = (size_t)(mb * 32 + 16 + l4 * 4 + r) * H_ + bcol;
                    whi[off] = hi; wlo[off] = lo;
                }
            }
        }
        __syncthreads();   // h stores drained (barrier implies waitcnt)

        // ---- distributed grid barrier ----
        if (tid == 0) {
            // release: write back dirty L2 (h tile), then signal arrival
            __hip_atomic_store(arrive, (unsigned)(t + 1), __ATOMIC_RELEASE, __HIP_MEMORY_SCOPE_AGENT);
        }
        if (wg == 0) {
            if (tid < NWG) {
                unsigned int* slot = flags + 16 + tid * 16;
                while (__hip_atomic_load(slot, __ATOMIC_RELAXED, __HIP_MEMORY_SCOPE_AGENT) < (unsigned)(t + 1))
                    __builtin_amdgcn_s_sleep(2);
            }
            __syncthreads();
            if (tid == 0) {
                // release store: orders the arrive-reads before go becomes visible
                __hip_atomic_store(gof, (unsigned)(t + 1), __ATOMIC_RELEASE, __HIP_MEMORY_SCOPE_AGENT);
            }
        }
        if (tid == 0) {
            while (__hip_atomic_load(gof, __ATOMIC_RELAXED, __HIP_MEMORY_SCOPE_AGENT) < (unsigned)(t + 1))
                __builtin_amdgcn_s_sleep(2);
            __builtin_amdgcn_fence(__ATOMIC_ACQUIRE, "agent");  // invalidate stale h lines
        }
        __syncthreads();
    }

    // ---- epilogue: logits + softmax, one WG per batch row (h_T in buf1) ----
    if (wg < B_) {
        const int b = wg;
        float o[O_];
#pragma unroll
        for (int j = 0; j < O_; ++j) o[j] = 0.f;
        for (int k = tid; k < H_; k += NTHR) {
            const float hv = bf16_to_f(h_hi1[(size_t)b * H_ + k]) + bf16_to_f(h_lo1[(size_t)b * H_ + k]);
            const float* wrow = W_ph + (size_t)k * O_;
#pragma unroll
            for (int j = 0; j < O_; ++j) o[j] += hv * wrow[j];
        }
#pragma unroll
        for (int off = 32; off > 0; off >>= 1) {
#pragma unroll
            for (int j = 0; j < O_; ++j) o[j] += __shfl_down(o[j], off);
        }
        if (lane == 0) {
#pragma unroll
            for (int j = 0; j < O_; ++j) epi[wave * 16 + j] = o[j];
        }
        __syncthreads();
        if (tid < O_) {
            float l = b_o[tid];
#pragma unroll
            for (int w = 0; w < 8; ++w) l += epi[w * 16 + tid];
            lgt[tid] = l;
        }
        __syncthreads();
        if (tid < O_) {
            float m = lgt[0];
#pragma unroll
            for (int j = 1; j < O_; ++j) m = fmaxf(m, lgt[j]);
            float ssum = 0.f;
#pragma unroll
            for (int j = 0; j < O_; ++j) ssum += expf(lgt[j] - m);
            out[(size_t)b * O_ + tid] = expf(lgt[tid] - m) / ssum;
        }
    }
}

extern "C" void kernel_launch(void* const* d_in, const int* in_sizes, int n_in,
                              void* d_out, int out_size, void* d_ws, size_t ws_size,
                              hipStream_t stream) {
    const float* x    = (const float*)d_in[0];
    const float* Whx  = (const float*)d_in[1];
    const float* Whh  = (const float*)d_in[2];
    const float* bh   = (const float*)d_in[3];
    const float* Wph  = (const float*)d_in[4];
    const float* bo   = (const float*)d_in[5];
    float* out = (float*)d_out;

    // ws layout: flags (20KB) | Wt_hi | Wt_lo | h ping-pong (hi/lo x2)
    char* ws = (char*)d_ws;
    unsigned int*   flags = (unsigned int*)ws;
    unsigned short* Wt_hi = (unsigned short*)(ws + 20480);
    unsigned short* Wt_lo = Wt_hi + (size_t)H_ * KK;
    unsigned short* h_hi0 = Wt_lo + (size_t)H_ * KK;
    unsigned short* h_lo0 = h_hi0 + (size_t)B_ * H_;
    unsigned short* h_hi1 = h_lo0 + (size_t)B_ * H_;
    unsigned short* h_lo1 = h_hi1 + (size_t)B_ * H_;

    hipLaunchKernelGGL(prep_init, dim3(1), dim3(256), 0, stream, flags);
    hipLaunchKernelGGL(prep_weights, dim3(68, 64), dim3(256), 0, stream, Whh, Whx, Wt_hi, Wt_lo);

    void* args[] = {
        (void*)&x, (void*)&Wt_hi, (void*)&Wt_lo, (void*)&bh, (void*)&Wph, (void*)&bo,
        (void*)&h_hi0, (void*)&h_lo0, (void*)&h_hi1, (void*)&h_lo1, (void*)&out, (void*)&flags
    };
    hipLaunchCooperativeKernel((const void*)rnn_scan, dim3(NWG), dim3(NTHR), args, 0, stream);
}

// Round 3
// 6336.177 us; speedup vs baseline: 10.0466x; 1.9886x over previous
//
#include <hip/hip_runtime.h>
#include <stdint.h>

// VanillaRNN: B=128, T=512, I=128, H=2048, O=10
// h_{t+1} = tanh(x_t @ W_hx + h_t @ W_hh + b_h); out = softmax(h_T @ W_ph + b_o)
//
// R3: persistent coop kernel, 256 WGs = 8 row-blocks x 32 col-blocks,
//   WG tile = [16 rows x 64 cols]. 8 waves = 8-way k-split (no dup).
//   W single bf16 in registers (~144 VGPR). h hi/lo bf16 split.
//   h moves via coherent (sc0 sc1) loads/stores -> NO per-step L2 inv/wb.
//   Grid barrier: distributed arrive slots + go flag, relaxed polls.

#define B_   128
#define T_   512
#define I_   128
#define H_   2048
#define O_   10
#define KK   2176   // H_ + I_
#define NWG  256
#define NTHR 512

typedef __attribute__((ext_vector_type(8))) short bf16x8;
typedef __attribute__((ext_vector_type(4))) float f32x4;
typedef __attribute__((ext_vector_type(4))) int   i32x4;

__device__ __forceinline__ unsigned short bf16_rne(float f) {
    uint32_t u = __builtin_bit_cast(uint32_t, f);
    return (unsigned short)((u + 0x7FFFu + ((u >> 16) & 1u)) >> 16);
}
__device__ __forceinline__ float bf16_to_f(unsigned short h) {
    return __builtin_bit_cast(float, (uint32_t)h << 16);
}
__device__ __forceinline__ bf16x8 mk8(uint64_t a, uint64_t b) {
    i32x4 v;
    v[0] = (int)(uint32_t)a; v[1] = (int)(uint32_t)(a >> 32);
    v[2] = (int)(uint32_t)b; v[3] = (int)(uint32_t)(b >> 32);
    return __builtin_bit_cast(bf16x8, v);
}

// coherent (MALL-served) ops: bypass L1/L2, no fences needed
#define LD64CC(p) __hip_atomic_load((const uint64_t*)(p), __ATOMIC_RELAXED, __HIP_MEMORY_SCOPE_AGENT)
__device__ __forceinline__ void st16cc(unsigned short* p, unsigned short v) {
    asm volatile("global_store_short %0, %1, off sc0 sc1"
                 :: "v"((uint64_t)(uintptr_t)p), "v"((uint32_t)v) : "memory");
}

#define MFMA(a, b, c) __builtin_amdgcn_mfma_f32_16x16x32_bf16((a), (b), (c), 0, 0, 0)

__global__ void prep_init(unsigned int* flags) {
    for (int i = threadIdx.x; i < 5120; i += blockDim.x) flags[i] = 0u;
}

// Transpose to Wt[n][k] (single bf16): k<2048 -> W_hh, k>=2048 -> W_hx.
__global__ void prep_weights(const float* __restrict__ Whh, const float* __restrict__ Whx,
                             unsigned short* __restrict__ Wt) {
    __shared__ float tile[32][33];
    const int kt = blockIdx.x;          // 0..67
    const int nt = blockIdx.y;          // 0..63
    const int tx = threadIdx.x & 31;
    const int ty = threadIdx.x >> 5;
#pragma unroll
    for (int r = ty; r < 32; r += 8) {
        const int k = kt * 32 + r;
        const int n = nt * 32 + tx;
        tile[r][tx] = (k < H_) ? Whh[(size_t)k * H_ + n] : Whx[(size_t)(k - H_) * H_ + n];
    }
    __syncthreads();
#pragma unroll
    for (int r = ty; r < 32; r += 8) {
        const int n = nt * 32 + r;
        const int k = kt * 32 + tx;
        Wt[(size_t)n * KK + k] = bf16_rne(tile[tx][r]);
    }
}

__global__ __launch_bounds__(NTHR, 2) void rnn_scan(
    const float* __restrict__ x,              // [B][T][I]
    const unsigned short* __restrict__ Wt,    // [H][KK] bf16
    const float* __restrict__ b_h,
    const float* __restrict__ W_ph,           // [H][O]
    const float* __restrict__ b_o,
    unsigned short* __restrict__ h_hi0, unsigned short* __restrict__ h_lo0,
    unsigned short* __restrict__ h_hi1, unsigned short* __restrict__ h_lo1,
    float* __restrict__ out,                  // [B][O]
    unsigned int* __restrict__ flags)
{
    const int tid  = threadIdx.x;
    const int wg   = blockIdx.x;
    const int w    = tid >> 6;        // wave 0..7 = k-eighth
    const int lane = tid & 63;
    const int l15  = lane & 15;
    const int l4   = lane >> 4;
    const int rb   = wg >> 5;         // row block 0..7
    const int cb   = wg & 31;         // col block 0..31
    const int r0   = rb * 16;
    const int c0   = cb * 64;

    const int arow = r0 + l15;        // A row (batch row)

    unsigned int* gof    = flags;
    unsigned int* arrive = flags + 16 + wg * 16;

    __shared__ f32x4 red[8][4][64];   // [wave][ntile][lane]
    __shared__ float epi[128];
    __shared__ float lgt[16];

    // ---- preload W panel into registers (single bf16, const over t) ----
    i32x4 wh[4][8];
    i32x4 wx[4];
    {
#pragma unroll
        for (int n = 0; n < 4; ++n) {
            const size_t colbase = (size_t)(c0 + n * 16 + l15) * KK;
#pragma unroll
            for (int j = 0; j < 8; ++j)
                wh[n][j] = *(const i32x4*)(Wt + colbase + (size_t)(w * 256 + j * 32 + l4 * 8));
            if (w >= 4)
                wx[n] = *(const i32x4*)(Wt + colbase + (size_t)(2048 + (w - 4) * 32 + l4 * 8));
        }
    }

    // reducer-thread constants (valid for tid < 256)
    const int rn   = tid >> 6;
    const int rL   = tid & 63;
    const int rcol = c0 + rn * 16 + (rL & 15);
    const int rrow0 = r0 + (rL >> 4) * 4;
    const float rbias = b_h[rcol];

    for (int t = 0; t < T_; ++t) {
        const unsigned short* rhi = (t & 1) ? h_hi0 : h_hi1;
        const unsigned short* rlo = (t & 1) ? h_lo0 : h_lo1;
        unsigned short* whi = (t & 1) ? h_hi1 : h_hi0;
        unsigned short* wlo = (t & 1) ? h_lo1 : h_lo0;

        f32x4 acc[4];
#pragma unroll
        for (int n = 0; n < 4; ++n) acc[n] = f32x4{0.f, 0.f, 0.f, 0.f};

        // ---- x contribution (waves 4..7 own the 4 x k-tiles) ----
        if (w >= 4) {
            const float* xp = x + ((size_t)arow * T_ + t) * I_ + (size_t)((w - 4) * 32 + l4 * 8);
            const f32x4 xa = *(const f32x4*)xp;
            const f32x4 xb = *(const f32x4*)(xp + 4);
            bf16x8 xh, xl;
#pragma unroll
            for (int jj = 0; jj < 8; ++jj) {
                const float f = (jj < 4) ? xa[jj] : xb[jj - 4];
                const unsigned short hi = bf16_rne(f);
                xh[jj] = (short)hi;
                xl[jj] = (short)bf16_rne(f - bf16_to_f(hi));
            }
#pragma unroll
            for (int n = 0; n < 4; ++n) acc[n] = MFMA(xh, wx[n], acc[n]);
#pragma unroll
            for (int n = 0; n < 4; ++n) acc[n] = MFMA(xl, wx[n], acc[n]);
        }

        // ---- h contribution: this wave's k-eighth, coherent loads ----
        if (t > 0) {
            const size_t base = (size_t)arow * H_ + (size_t)(w * 256 + l4 * 8);
#pragma unroll
            for (int j = 0; j < 8; ++j) {
                const unsigned short* ph = rhi + base + j * 32;
                const unsigned short* pl = rlo + base + j * 32;
                const uint64_t h0 = LD64CC(ph);
                const uint64_t h1 = LD64CC(ph + 4);
                const uint64_t g0 = LD64CC(pl);
                const uint64_t g1 = LD64CC(pl + 4);
                const bf16x8 ah = mk8(h0, h1);
                const bf16x8 al = mk8(g0, g1);
#pragma unroll
                for (int n = 0; n < 4; ++n) acc[n] = MFMA(ah, wh[n][j], acc[n]);
#pragma unroll
                for (int n = 0; n < 4; ++n) acc[n] = MFMA(al, wh[n][j], acc[n]);
            }
        }

        // ---- cross-wave k-reduce via LDS ----
#pragma unroll
        for (int n = 0; n < 4; ++n) red[w][n][lane] = acc[n];
        __syncthreads();

        if (tid < 256) {
            f32x4 v = red[0][rn][rL];
#pragma unroll
            for (int p = 1; p < 8; ++p) v += red[p][rn][rL];
#pragma unroll
            for (int r = 0; r < 4; ++r) {
                const float hv = tanhf(v[r] + rbias);
                const unsigned short hi = bf16_rne(hv);
                const unsigned short lo = bf16_rne(hv - bf16_to_f(hi));
                const size_t off = (size_t)(rrow0 + r) * H_ + rcol;
                st16cc(whi + off, hi);
                st16cc(wlo + off, lo);
            }
        }
        __syncthreads();   // drains the coherent stores (vmcnt 0 at barrier)

        // ---- grid barrier: flags only, no cache maintenance ----
        if (tid == 0)
            __hip_atomic_store(arrive, (unsigned)(t + 1), __ATOMIC_RELEASE, __HIP_MEMORY_SCOPE_AGENT);
        if (wg == 0) {
            if (tid < NWG) {
                unsigned int* slot = flags + 16 + tid * 16;
                while (__hip_atomic_load(slot, __ATOMIC_RELAXED, __HIP_MEMORY_SCOPE_AGENT) < (unsigned)(t + 1))
                    __builtin_amdgcn_s_sleep(1);
            }
            __syncthreads();
            if (tid == 0)
                __hip_atomic_store(gof, (unsigned)(t + 1), __ATOMIC_RELEASE, __HIP_MEMORY_SCOPE_AGENT);
        }
        if (tid == 0) {
            while (__hip_atomic_load(gof, __ATOMIC_RELAXED, __HIP_MEMORY_SCOPE_AGENT) < (unsigned)(t + 1))
                __builtin_amdgcn_s_sleep(1);
        }
        __syncthreads();
    }

    // ---- epilogue: logits + softmax, one WG per batch row (h_T in buf1) ----
    if (wg < B_) {
        const int b = wg;
        float o[O_];
#pragma unroll
        for (int j = 0; j < O_; ++j) o[j] = 0.f;
        for (int k = tid; k < H_; k += NTHR) {
            const float hv = bf16_to_f(h_hi1[(size_t)b * H_ + k]) + bf16_to_f(h_lo1[(size_t)b * H_ + k]);
            const float* wrow = W_ph + (size_t)k * O_;
#pragma unroll
            for (int j = 0; j < O_; ++j) o[j] += hv * wrow[j];
        }
#pragma unroll
        for (int off = 32; off > 0; off >>= 1) {
#pragma unroll
            for (int j = 0; j < O_; ++j) o[j] += __shfl_down(o[j], off);
        }
        if (lane == 0) {
#pragma unroll
            for (int j = 0; j < O_; ++j) epi[w * 16 + j] = o[j];
        }
        __syncthreads();
        if (tid < O_) {
            float l = b_o[tid];
#pragma unroll
            for (int ww = 0; ww < 8; ++ww) l += epi[ww * 16 + tid];
            lgt[tid] = l;
        }
        __syncthreads();
        if (tid < O_) {
            float m = lgt[0];
#pragma unroll
            for (int j = 1; j < O_; ++j) m = fmaxf(m, lgt[j]);
            float ssum = 0.f;
#pragma unroll
            for (int j = 0; j < O_; ++j) ssum += expf(lgt[j] - m);
            out[(size_t)b * O_ + tid] = expf(lgt[tid] - m) / ssum;
        }
    }
}

extern "C" void kernel_launch(void* const* d_in, const int* in_sizes, int n_in,
                              void* d_out, int out_size, void* d_ws, size_t ws_size,
                              hipStream_t stream) {
    const float* x    = (const float*)d_in[0];
    const float* Whx  = (const float*)d_in[1];
    const float* Whh  = (const float*)d_in[2];
    const float* bh   = (const float*)d_in[3];
    const float* Wph  = (const float*)d_in[4];
    const float* bo   = (const float*)d_in[5];
    float* out = (float*)d_out;

    // ws layout: flags (20KB) | Wt (8.9MB) | h ping-pong (hi/lo x2, 512KB each)
    char* ws = (char*)d_ws;
    unsigned int*   flags = (unsigned int*)ws;
    unsigned short* Wt    = (unsigned short*)(ws + 20480);
    unsigned short* h_hi0 = Wt + (size_t)H_ * KK;
    unsigned short* h_lo0 = h_hi0 + (size_t)B_ * H_;
    unsigned short* h_hi1 = h_lo0 + (size_t)B_ * H_;
    unsigned short* h_lo1 = h_hi1 + (size_t)B_ * H_;

    hipLaunchKernelGGL(prep_init, dim3(1), dim3(256), 0, stream, flags);
    hipLaunchKernelGGL(prep_weights, dim3(68, 64), dim3(256), 0, stream, Whh, Whx, Wt);

    void* args[] = {
        (void*)&x, (void*)&Wt, (void*)&bh, (void*)&Wph, (void*)&bo,
        (void*)&h_hi0, (void*)&h_lo0, (void*)&h_hi1, (void*)&h_lo1, (void*)&out, (void*)&flags
    };
    hipLaunchCooperativeKernel((const void*)rnn_scan, dim3(NWG), dim3(NTHR), args, 0, stream);
}

// Round 6
// 4083.394 us; speedup vs baseline: 15.5893x; 1.5517x over previous
//
#include <hip/hip_runtime.h>
#include <stdint.h>

// VanillaRNN: B=128, T=512, I=128, H=2048, O=10
// R6: proven-primitive rebuild of R3, all-f16 datapath.
//   - 256 WGs, WG tile [16 rows x 64 cols], 8 waves = 8-way k-split.
//   - W (f16, transposed) in registers (~144 VGPR); h single f16 ping-pong.
//   - h stores: sc0 sc1 write-through (R3-proven). h loads: burst of
//     global_load_dwordx4 sc1 (agent scope) + counted vmcnt drain.
//   - Flat 1-hop barrier: each WG's 256 threads poll all 256 arrive slots.

#define B_   128
#define T_   512
#define I_   128
#define H_   2048
#define O_   10
#define KK   2176
#define NWG  256
#define NTHR 512

typedef __attribute__((ext_vector_type(8))) _Float16 f16x8;
typedef __attribute__((ext_vector_type(4))) float    f32x4;
typedef __attribute__((ext_vector_type(4))) int      i32x4;

__device__ __forceinline__ float f16_to_f(unsigned short u) {
    return (float)__builtin_bit_cast(_Float16, u);
}
__device__ __forceinline__ unsigned short f_to_f16(float f) {
    return __builtin_bit_cast(unsigned short, (_Float16)f);
}

// system-scope coherent store (R3-proven): write-through to MALL
__device__ __forceinline__ void st16cc(unsigned short* p, unsigned short v) {
    asm volatile("global_store_short %0, %1, off sc0 sc1"
                 :: "v"((uint64_t)(uintptr_t)p), "v"((uint32_t)v) : "memory");
}

#define MFMA16(a, b, c) __builtin_amdgcn_mfma_f32_16x16x32_f16((a), (b), (c), 0, 0, 0)

__global__ void prep_init(unsigned int* flags) {
    for (int i = threadIdx.x; i < 8192; i += blockDim.x) flags[i] = 0u;
}

// Transpose + f16 convert: Wt[n][k]; k<2048 -> W_hh, k>=2048 -> W_hx.
__global__ void prep_weights(const float* __restrict__ Whh, const float* __restrict__ Whx,
                             unsigned short* __restrict__ Wt) {
    __shared__ float tile[32][33];
    const int kt = blockIdx.x;          // 0..67
    const int nt = blockIdx.y;          // 0..63
    const int tx = threadIdx.x & 31;
    const int ty = threadIdx.x >> 5;
#pragma unroll
    for (int r = ty; r < 32; r += 8) {
        const int k = kt * 32 + r;
        const int n = nt * 32 + tx;
        tile[r][tx] = (k < H_) ? Whh[(size_t)k * H_ + n] : Whx[(size_t)(k - H_) * H_ + n];
    }
    __syncthreads();
#pragma unroll
    for (int r = ty; r < 32; r += 8) {
        const int n = nt * 32 + r;
        const int k = kt * 32 + tx;
        Wt[(size_t)n * KK + k] = f_to_f16(tile[tx][r]);
    }
}

__global__ __launch_bounds__(NTHR, 2) void rnn_scan(
    const float* __restrict__ x,              // [B][T][I] f32
    const unsigned short* __restrict__ Wt,    // [H][KK] f16
    const float* __restrict__ b_h,
    const float* __restrict__ W_ph,           // [H][O]
    const float* __restrict__ b_o,
    unsigned short* __restrict__ h0,          // [B][H] f16 ping
    unsigned short* __restrict__ h1,          // [B][H] f16 pong
    float* __restrict__ out,                  // [B][O]
    unsigned int* __restrict__ flags)
{
    const int tid  = threadIdx.x;
    const int wg   = blockIdx.x;
    const int w    = tid >> 6;        // wave 0..7 = k-eighth
    const int lane = tid & 63;
    const int l15  = lane & 15;
    const int l4   = lane >> 4;
    const int rb   = wg >> 5;         // row block 0..7
    const int cb   = wg & 31;         // col block 0..31
    const int r0   = rb * 16;
    const int c0   = cb * 64;
    const int arow = r0 + l15;

    __shared__ f32x4 red[8][4][64];   // [wave][ntile][lane]  (32 KB)
    __shared__ float epi[128];
    __shared__ float lgt[16];

    // ---- W panel into registers (f16, const over t) ----
    i32x4 wh[4][8];
    i32x4 wx[4];
#pragma unroll
    for (int n = 0; n < 4; ++n) {
        const size_t colbase = (size_t)(c0 + n * 16 + l15) * KK;
#pragma unroll
        for (int j = 0; j < 8; ++j)
            wh[n][j] = *(const i32x4*)(Wt + colbase + (size_t)(w * 256 + j * 32 + l4 * 8));
        if (w >= 4)
            wx[n] = *(const i32x4*)(Wt + colbase + (size_t)(2048 + (w - 4) * 32 + l4 * 8));
    }

    // reducer constants (tid < 256)
    const int rn    = tid >> 6;
    const int rL    = tid & 63;
    const int rcol  = c0 + rn * 16 + (rL & 15);
    const int rrow0 = r0 + (rL >> 4) * 4;
    const float rbias = b_h[rcol];

    for (int t = 0; t < T_; ++t) {
        const unsigned short* rh = (t & 1) ? h0 : h1;   // read buf (written t-1)
        unsigned short*       wh_ = (t & 1) ? h1 : h0;  // write buf

        f32x4 acc[4];
#pragma unroll
        for (int n = 0; n < 4; ++n) acc[n] = f32x4{0.f, 0.f, 0.f, 0.f};

        // ---- x contribution (waves 4..7 own the 4 x k-tiles) ----
        if (w >= 4) {
            const float* xp = x + ((size_t)arow * T_ + t) * I_ + (size_t)((w - 4) * 32 + l4 * 8);
            const f32x4 xa = *(const f32x4*)xp;
            const f32x4 xb = *(const f32x4*)(xp + 4);
            f16x8 xv;
#pragma unroll
            for (int jj = 0; jj < 8; ++jj)
                xv[jj] = (_Float16)((jj < 4) ? xa[jj] : xb[jj - 4]);
#pragma unroll
            for (int n = 0; n < 4; ++n)
                acc[n] = MFMA16(xv, __builtin_bit_cast(f16x8, wx[n]), acc[n]);
        }

        // ---- h contribution: this wave's k-eighth, burst + counted drain ----
        if (t > 0) {
            const uint64_t base64 = (uint64_t)(uintptr_t)(rh + (size_t)arow * H_ + (size_t)(w * 256 + l4 * 8));
            i32x4 hb[8];
#define ISSJ(jj, IMM) \
    asm volatile("global_load_dwordx4 %0, %1, off offset:" IMM " sc1" \
                 : "=v"(hb[jj]) : "v"(base64) : "memory")
#define WAITV(NSTR) do { \
    asm volatile("s_waitcnt vmcnt(" NSTR ")" ::: "memory"); \
    __builtin_amdgcn_sched_barrier(0); } while (0)
#define CONS(jj) do { \
    const f16x8 AH = __builtin_bit_cast(f16x8, hb[jj]); \
    acc[0] = MFMA16(AH, __builtin_bit_cast(f16x8, wh[0][jj]), acc[0]); \
    acc[1] = MFMA16(AH, __builtin_bit_cast(f16x8, wh[1][jj]), acc[1]); \
    acc[2] = MFMA16(AH, __builtin_bit_cast(f16x8, wh[2][jj]), acc[2]); \
    acc[3] = MFMA16(AH, __builtin_bit_cast(f16x8, wh[3][jj]), acc[3]); \
    } while (0)

            ISSJ(0, "0");   ISSJ(1, "64");  ISSJ(2, "128"); ISSJ(3, "192");
            ISSJ(4, "256"); ISSJ(5, "320"); ISSJ(6, "384"); ISSJ(7, "448");
            WAITV("7"); CONS(0);
            WAITV("6"); CONS(1);
            WAITV("5"); CONS(2);
            WAITV("4"); CONS(3);
            WAITV("3"); CONS(4);
            WAITV("2"); CONS(5);
            WAITV("1"); CONS(6);
            WAITV("0"); CONS(7);
#undef ISSJ
#undef WAITV
#undef CONS
        }

        // ---- cross-wave k-reduce via LDS ----
#pragma unroll
        for (int n = 0; n < 4; ++n) red[w][n][lane] = acc[n];
        __syncthreads();

        if (tid < 256) {
            f32x4 v = red[0][rn][rL];
#pragma unroll
            for (int p = 1; p < 8; ++p) v += red[p][rn][rL];
#pragma unroll
            for (int r = 0; r < 4; ++r) {
                const float hv = tanhf(v[r] + rbias);
                st16cc(wh_ + (size_t)(rrow0 + r) * H_ + rcol, f_to_f16(hv));
            }
        }
        asm volatile("s_waitcnt vmcnt(0)" ::: "memory");   // own h stores at MALL
        __syncthreads();

        // ---- flat 1-hop grid barrier ----
        if (tid == 0)
            __hip_atomic_store(flags + 16 + (size_t)wg * 16, (unsigned)(t + 1),
                               __ATOMIC_RELEASE, __HIP_MEMORY_SCOPE_AGENT);
        if (tid < NWG) {
            unsigned int* slot = flags + 16 + (size_t)tid * 16;
            while (__hip_atomic_load(slot, __ATOMIC_RELAXED, __HIP_MEMORY_SCOPE_AGENT) < (unsigned)(t + 1))
                __builtin_amdgcn_s_sleep(1);
        }
        __syncthreads();
    }

    // ---- epilogue: logits + softmax, one WG per batch row (h_T in h1) ----
    if (wg < B_) {
        const int b = wg;
        float o[O_];
#pragma unroll
        for (int j = 0; j < O_; ++j) o[j] = 0.f;
        for (int k = tid; k < H_; k += NTHR) {
            const float hv = f16_to_f(h1[(size_t)b * H_ + k]);
            const float* wrow = W_ph + (size_t)k * O_;
#pragma unroll
            for (int j = 0; j < O_; ++j) o[j] += hv * wrow[j];
        }
#pragma unroll
        for (int off = 32; off > 0; off >>= 1) {
#pragma unroll
            for (int j = 0; j < O_; ++j) o[j] += __shfl_down(o[j], off);
        }
        if (lane == 0) {
#pragma unroll
            for (int j = 0; j < O_; ++j) epi[w * 16 + j] = o[j];
        }
        __syncthreads();
        if (tid < O_) {
            float l = b_o[tid];
#pragma unroll
            for (int ww = 0; ww < 8; ++ww) l += epi[ww * 16 + tid];
            lgt[tid] = l;
        }
        __syncthreads();
        if (tid < O_) {
            float m = lgt[0];
#pragma unroll
            for (int j = 1; j < O_; ++j) m = fmaxf(m, lgt[j]);
            float ssum = 0.f;
#pragma unroll
            for (int j = 0; j < O_; ++j) ssum += expf(lgt[j] - m);
            out[(size_t)b * O_ + tid] = expf(lgt[tid] - m) / ssum;
        }
    }
}

extern "C" void kernel_launch(void* const* d_in, const int* in_sizes, int n_in,
                              void* d_out, int out_size, void* d_ws, size_t ws_size,
                              hipStream_t stream) {
    const float* x    = (const float*)d_in[0];
    const float* Whx  = (const float*)d_in[1];
    const float* Whh  = (const float*)d_in[2];
    const float* bh   = (const float*)d_in[3];
    const float* Wph  = (const float*)d_in[4];
    const float* bo   = (const float*)d_in[5];
    float* out = (float*)d_out;

    // ws: flags 32KB | Wt (f16, 8.9MB) | h ping-pong (f16, 512KB x2)
    char* ws = (char*)d_ws;
    unsigned int*   flags = (unsigned int*)ws;
    unsigned short* Wt    = (unsigned short*)(ws + 32768);
    unsigned short* h0    = Wt + (size_t)H_ * KK;
    unsigned short* h1    = h0 + (size_t)B_ * H_;

    hipLaunchKernelGGL(prep_init, dim3(1), dim3(256), 0, stream, flags);
    hipLaunchKernelGGL(prep_weights, dim3(68, 64), dim3(256), 0, stream, Whh, Whx, Wt);

    void* args[] = {
        (void*)&x, (void*)&Wt, (void*)&bh, (void*)&Wph, (void*)&bo,
        (void*)&h0, (void*)&h1, (void*)&out, (void*)&flags
    };
    hipLaunchCooperativeKernel((const void*)rnn_scan, dim3(NWG), dim3(NTHR), args, 0, stream);
}